// Round 11
// baseline (838.823 us; speedup 1.0000x reference)
//
#include <hip/hip_runtime.h>

#define Bsz 1024
#define Tn  256
#define Fn  128

typedef float f32x4 __attribute__((ext_vector_type(4)));
typedef float v2f   __attribute__((ext_vector_type(2)));
typedef short s16x8 __attribute__((ext_vector_type(8)));

#define LOG2E 1.44269504088896f
#define L2E2  2.88539008177793f

__device__ __forceinline__ float frcp(float x)  { return __builtin_amdgcn_rcpf(x); }
__device__ __forceinline__ unsigned bf16bits(float v) {   // RNE f32 -> bf16 bits
    unsigned x = __float_as_uint(v);
    return (x + 0x7FFFu + ((x >> 16) & 1u)) >> 16;
}
__device__ __forceinline__ float fromhi(unsigned hb) { return __uint_as_float(hb << 16); }
__device__ __forceinline__ unsigned cvtpk(float a, float b) {  // low=bf16(a), high=bf16(b)
    unsigned r; asm("v_cvt_pk_bf16_f32 %0, %1, %2" : "=v"(r) : "v"(a), "v"(b)); return r;
}

union FragU { unsigned u[4]; s16x8 v; };

// ---------- packed polynomial exp2 (full-rate VALU, no trans pipe) ----------
// 2^g = 2^round(g) * poly5(frac); round via magic-add (RNE, |g|<2^22);
// scale via integer add to exponent field ((bits(t)<<23) == round(g)<<23
// since the magic's low 9 mantissa bits are 0). Requires g >= -126.
__device__ __forceinline__ v2f exp2p(v2f g) {
    const v2f MAGIC = (v2f)12582912.0f;            // 1.5 * 2^23
    const v2f t = g + MAGIC;
    const v2f r = t - MAGIC;
    const v2f f = g - r;                           // |f| <= 0.5
    v2f p = __builtin_elementwise_fma(f, (v2f)0.0013333558f, (v2f)0.0096181291f);
    p = __builtin_elementwise_fma(p, f, (v2f)0.0555041086f);
    p = __builtin_elementwise_fma(p, f, (v2f)0.2402265069f);
    p = __builtin_elementwise_fma(p, f, (v2f)0.6931471806f);
    p = __builtin_elementwise_fma(p, f, (v2f)1.0f);
    const unsigned e0 = __float_as_uint(t.x) << 23;
    const unsigned e1 = __float_as_uint(t.y) << 23;
    return v2f{__uint_as_float(__float_as_uint(p.x) + e0),
               __uint_as_float(__float_as_uint(p.y) + e1)};
}

// ---------- packed 2-cell LSTM activation (exp2 domain, poly exp) ----------
__device__ __forceinline__ v2f act_pair(v2f gi, v2f gf, v2f gg, v2f go, v2f& c2) {
    const v2f one = (v2f)1.0f;
    const v2f Ei = exp2p(gi);
    const v2f Ef = exp2p(gf);
    const v2f Eg = exp2p(gg);
    const v2f Eo = exp2p(go);
    const v2f pf  = one + Ef;
    const v2f pig = (one + Ei) * (one + Eg);
    const v2f p3  = pig * pf;
    const float Rm = frcp(p3.x * p3.y);            // pair-shared reciprocal
    const v2f R3  = {Rm * p3.y, Rm * p3.x};
    const v2f Rf  = pig * R3;                      // sigmoid(f)
    const v2f Rig = pf  * R3;                      // 1/((1+Ei)(1+Eg))
    const v2f cn  = __builtin_elementwise_fma(c2, Rf, (Eg - one) * Rig);
    c2 = cn;
    v2f cs = __builtin_elementwise_min(cn * (v2f)L2E2, (v2f)40.0f);
    cs = __builtin_elementwise_max(cs, (v2f)-126.0f);   // exp2p bit-trick domain
    const v2f Ec  = exp2p(cs);
    const v2f den = (one + Eo) * (one + Ec);
    const float Rd = frcp(den.x * den.y);          // pair-shared reciprocal
    const v2f Roc = {Rd * den.y, Rd * den.x};
    return (Ec - one) * Roc;                       // o * tanh(c)
}

// ---------- kernel 1: transpose x (B,T,F) f32 -> (T,F,B) packed (lo16<<16 | hi16) ----------
__global__ __launch_bounds__(256) void transpose_pack(const float* __restrict__ x,
                                                      unsigned* __restrict__ xt) {
    __shared__ float tile[32][33];
    const int t  = blockIdx.z;
    const int bb = blockIdx.x * 32;
    const int ff = blockIdx.y * 32;
    const int tx = threadIdx.x;   // 0..31
    const int ty = threadIdx.y;   // 0..7
#pragma unroll
    for (int i = 0; i < 4; ++i) {
        int brow = ty + i * 8;
        tile[brow][tx] = x[((size_t)(bb + brow) * Tn + t) * Fn + (ff + tx)];
    }
    __syncthreads();
#pragma unroll
    for (int i = 0; i < 4; ++i) {
        int frow = ty + i * 8;
        float v = tile[tx][frow];
        unsigned hb = bf16bits(v);
        unsigned lb = bf16bits(v - fromhi(hb));
        xt[((size_t)t * Fn + (ff + frow)) * Bsz + (bb + tx)] = hb | (lb << 16);
    }
}

// ---------- kernel 2: recurrent LSTM via MFMA, zero LDS ----------
// wave = 1 feature x 16 batches; lane (col,gq) owns D rows 4gq..4gq+3 of
// batch col, and (by the shared believed k-map, validated r7-r10) its OWN
// B-fragment slots -> B built entirely in registers.
//   acc = MFMA(A1=[W_hi|W_hi], B1=[h_hi;h_lo],
//         MFMA(A2=[W_lo | wx,bias], B2=[h_hi; x,ones], ZERO))
// bias rides in A2 word3 against a constant bf16 {1,1} in B2 word3 (only
// gq==0 lanes carry it), freeing the 16-reg fp32 C-in -> occupancy up.
__global__ __launch_bounds__(256, 4) void lstm_fwd(const unsigned* __restrict__ xt,  // (T,F,B) packed
                                                   const float* __restrict__ Wih,    // (F,64)
                                                   const float* __restrict__ Whh,    // (F,64,16)
                                                   const float* __restrict__ bih,    // (F,64)
                                                   const float* __restrict__ bhh,    // (F,64)
                                                   const float* __restrict__ init_h,
                                                   const float* __restrict__ init_c,
                                                   float* __restrict__ hout) {       // (B, F*16)
    const int tid  = threadIdx.x;
    const int wv   = tid >> 6;
    const int lane = tid & 63;
    const int gq   = lane >> 4;          // k-quad group / D-row-group
    const int col  = lane & 15;          // A: M-row; B,D: batch col
    const int f    = blockIdx.x >> 4;
    const int bc   = ((blockIdx.x & 15) << 2) | wv;
    const int bglob = bc * 16 + col;

    // ---- persistent fragments (weights pre-scaled into exp2 domain) ----
    s16x8 A1[4], A2[4];
#pragma unroll
    for (int g = 0; g < 4; ++g) {
        const float s = (g == 2) ? L2E2 : -LOG2E;
        const float* wrow = Whh + ((size_t)f * 64 + g * 16 + col) * 16;
        float v0 = wrow[4 * gq + 0] * s, v1 = wrow[4 * gq + 1] * s;
        float v2 = wrow[4 * gq + 2] * s, v3 = wrow[4 * gq + 3] * s;
        unsigned h0 = bf16bits(v0), h1 = bf16bits(v1);
        unsigned h2 = bf16bits(v2), h3 = bf16bits(v3);
        FragU a1, a2;
        a1.u[0] = h0 | (h1 << 16);
        a1.u[1] = h2 | (h3 << 16);
        a1.u[2] = a1.u[0];               // W_hi pairs h_lo too
        a1.u[3] = a1.u[1];
        a2.u[0] = bf16bits(v0 - fromhi(h0)) | (bf16bits(v1 - fromhi(h1)) << 16);
        a2.u[1] = bf16bits(v2 - fromhi(h2)) | (bf16bits(v3 - fromhi(h3)) << 16);
        // x-slots (pair with B2 word2 = {x_hi, x_lo}):
        const float wx = Wih[(size_t)f * 64 + g * 16 + col] * s;
        const unsigned wxh = bf16bits(wx);
        const unsigned wxl = bf16bits(wx - fromhi(wxh));
        a2.u[2] = (gq == 0) ? (wxh | (wxh << 16))      // wx_hi*x_hi + wx_hi*x_lo
                : (gq == 1) ? wxl : 0u;                // wx_lo*x_hi
        // bias slot (pairs with B2 word3 = bf16 {1,1}); only gq==0 carries it
        const float bsum = (bih[(size_t)f * 64 + g * 16 + col] +
                            bhh[(size_t)f * 64 + g * 16 + col]) * s;
        const unsigned bh = bf16bits(bsum);
        const unsigned bl = bf16bits(bsum - fromhi(bh));
        a2.u[3] = (gq == 0) ? (bh | (bl << 16)) : 0u;
        A1[g] = a1.v;  A2[g] = a2.v;
    }
    const f32x4 kZero = {0.0f, 0.0f, 0.0f, 0.0f};
    const unsigned ONES = 0x3F803F80u;   // bf16 {1.0, 1.0}

    v2f c01, c23, h01, h23;
    {
        const int base = f * 16 + gq * 4;
        c01 = v2f{init_c[base + 0], init_c[base + 1]};
        c23 = v2f{init_c[base + 2], init_c[base + 3]};
        h01 = v2f{init_h[base + 0], init_h[base + 1]};
        h23 = v2f{init_h[base + 2], init_h[base + 3]};
    }

    unsigned p0, p1, q0, q1;   // B1 words: h_hi pairs, h_lo pairs (registers)
#define REBUILD_B1()                                                            \
    {                                                                           \
        p0 = cvtpk(h01.x, h01.y);                                               \
        p1 = cvtpk(h23.x, h23.y);                                               \
        const float l0 = h01.x - __uint_as_float(p0 << 16);                     \
        const float l1 = h01.y - __uint_as_float(p0 & 0xFFFF0000u);             \
        const float l2 = h23.x - __uint_as_float(p1 << 16);                     \
        const float l3 = h23.y - __uint_as_float(p1 & 0xFFFF0000u);             \
        q0 = cvtpk(l0, l1);                                                     \
        q1 = cvtpk(l2, l3);                                                     \
    }
    REBUILD_B1();

    const unsigned* __restrict__ xp = xt + (size_t)f * Bsz + bglob;
    unsigned xw = xp[0];

    for (int t = 0; t < Tn; ++t) {
        const unsigned xnext = xp[(t + 1 < Tn) ? Fn * Bsz : 0];
        xp += Fn * Bsz;

        FragU b1, b2;
        b1.u[0] = p0; b1.u[1] = p1; b1.u[2] = q0; b1.u[3] = q1;
        b2.u[0] = p0; b2.u[1] = p1; b2.u[2] = xw; b2.u[3] = ONES;

        f32x4 acc0 = __builtin_amdgcn_mfma_f32_16x16x32_bf16(A2[0], b2.v, kZero, 0, 0, 0);
        f32x4 acc1 = __builtin_amdgcn_mfma_f32_16x16x32_bf16(A2[1], b2.v, kZero, 0, 0, 0);
        f32x4 acc2 = __builtin_amdgcn_mfma_f32_16x16x32_bf16(A2[2], b2.v, kZero, 0, 0, 0);
        f32x4 acc3 = __builtin_amdgcn_mfma_f32_16x16x32_bf16(A2[3], b2.v, kZero, 0, 0, 0);
        acc0 = __builtin_amdgcn_mfma_f32_16x16x32_bf16(A1[0], b1.v, acc0, 0, 0, 0);
        acc1 = __builtin_amdgcn_mfma_f32_16x16x32_bf16(A1[1], b1.v, acc1, 0, 0, 0);
        acc2 = __builtin_amdgcn_mfma_f32_16x16x32_bf16(A1[2], b1.v, acc2, 0, 0, 0);
        acc3 = __builtin_amdgcn_mfma_f32_16x16x32_bf16(A1[3], b1.v, acc3, 0, 0, 0);

        h01 = act_pair(__builtin_shufflevector(acc0, acc0, 0, 1),
                       __builtin_shufflevector(acc1, acc1, 0, 1),
                       __builtin_shufflevector(acc2, acc2, 0, 1),
                       __builtin_shufflevector(acc3, acc3, 0, 1), c01);
        h23 = act_pair(__builtin_shufflevector(acc0, acc0, 2, 3),
                       __builtin_shufflevector(acc1, acc1, 2, 3),
                       __builtin_shufflevector(acc2, acc2, 2, 3),
                       __builtin_shufflevector(acc3, acc3, 2, 3), c23);

        REBUILD_B1();
        xw = xnext;
    }

    *(f32x4*)(&hout[(size_t)bglob * (Fn * 16) + f * 16 + gq * 4]) =
        f32x4{h01.x, h01.y, h23.x, h23.y};
}

// ---------- kernel 3: out[b] = b_fuse + sum_k hout[b][k]*W_fuse[k] ----------
__global__ __launch_bounds__(256) void fuse_out(const float* __restrict__ hout,
                                                const float* __restrict__ Wf,
                                                const float* __restrict__ bfu,
                                                float* __restrict__ out) {
    __shared__ float part[4];
    const int b = blockIdx.x, tid = threadIdx.x;
    float acc = 0.0f;
#pragma unroll
    for (int q = 0; q < 8; ++q) {
        const int k = q * 256 + tid;
        acc = __fmaf_rn(hout[(size_t)b * (Fn * 16) + k], Wf[k], acc);
    }
#pragma unroll
    for (int off = 32; off; off >>= 1) acc += __shfl_down(acc, off, 64);
    if ((tid & 63) == 0) part[tid >> 6] = acc;
    __syncthreads();
    if (tid == 0) out[b] = part[0] + part[1] + part[2] + part[3] + bfu[0];
}

extern "C" void kernel_launch(void* const* d_in, const int* in_sizes, int n_in,
                              void* d_out, int out_size, void* d_ws, size_t ws_size,
                              hipStream_t stream) {
    const float* x      = (const float*)d_in[0];
    const float* Wih    = (const float*)d_in[1];
    const float* Whh    = (const float*)d_in[2];
    const float* bih    = (const float*)d_in[3];
    const float* bhh    = (const float*)d_in[4];
    const float* init_h = (const float*)d_in[5];
    const float* init_c = (const float*)d_in[6];
    const float* Wf     = (const float*)d_in[7];
    const float* bf     = (const float*)d_in[8];
    float* out = (float*)d_out;

    char* ws = (char*)d_ws;
    unsigned* xtp = (unsigned*)ws;                      // (T,F,B) u32 = 134,217,728 B
    float* hout   = (float*)(ws + (size_t)134217728);   // (B, F*16) = 8,388,608 B

    transpose_pack<<<dim3(32, 4, 256), dim3(32, 8), 0, stream>>>(x, xtp);
    lstm_fwd<<<2048, 256, 0, stream>>>(xtp, Wih, Whh, bih, bhh, init_h, init_c, hout);
    fuse_out<<<Bsz, 256, 0, stream>>>(hout, Wf, bf, out);
}

// Round 12
// 517.604 us; speedup vs baseline: 1.6206x; 1.6206x over previous
//
#include <hip/hip_runtime.h>

#define Bsz 1024
#define Tn  256
#define Fn  128

typedef float f32x4 __attribute__((ext_vector_type(4)));
typedef float v2f   __attribute__((ext_vector_type(2)));
typedef short s16x8 __attribute__((ext_vector_type(8)));

#define LOG2E 1.44269504088896f
#define L2E2  2.88539008177793f

__device__ __forceinline__ float frcp(float x)  { return __builtin_amdgcn_rcpf(x); }
__device__ __forceinline__ float fexp2(float x) { return __builtin_amdgcn_exp2f(x); }
__device__ __forceinline__ unsigned bf16bits(float v) {   // RNE f32 -> bf16 bits
    unsigned x = __float_as_uint(v);
    return (x + 0x7FFFu + ((x >> 16) & 1u)) >> 16;
}
__device__ __forceinline__ float fromhi(unsigned hb) { return __uint_as_float(hb << 16); }
__device__ __forceinline__ unsigned cvtpk(float a, float b) {  // low=bf16(a), high=bf16(b)
    unsigned r; asm("v_cvt_pk_bf16_f32 %0, %1, %2" : "=v"(r) : "v"(a), "v"(b)); return r;
}

union FragU { unsigned u[4]; s16x8 v; };

// ---------- packed 2-cell LSTM activation (exp2 domain, HW trans pipe) ----------
// 10 v_exp + 2 pair-shared v_rcp per 2 cells. cs clamped to 40 so the
// pair-product rcp can never overflow (den <= 2^52, product <= 2^104).
__device__ __forceinline__ v2f act_pair(v2f gi, v2f gf, v2f gg0, v2f go, v2f& c2) {
    const v2f one = (v2f)1.0f;
    const v2f gg = __builtin_elementwise_min(gg0, (v2f)100.0f);   // 0*inf guard
    const v2f Ei = {fexp2(gi.x), fexp2(gi.y)};
    const v2f Ef = {fexp2(gf.x), fexp2(gf.y)};
    const v2f Eg = {fexp2(gg.x), fexp2(gg.y)};
    const v2f Eo = {fexp2(go.x), fexp2(go.y)};
    const v2f pf  = one + Ef;
    const v2f pig = (one + Ei) * (one + Eg);
    const v2f p3  = pig * pf;
    const float Rm = frcp(p3.x * p3.y);            // pair-shared reciprocal
    const v2f R3  = {Rm * p3.y, Rm * p3.x};
    const v2f Rf  = pig * R3;                      // sigmoid(f)
    const v2f Rig = pf  * R3;                      // 1/((1+Ei)(1+Eg))
    const v2f cn  = __builtin_elementwise_fma(c2, Rf, (Eg - one) * Rig);
    c2 = cn;
    const v2f cs  = __builtin_elementwise_min(cn * (v2f)L2E2, (v2f)40.0f);
    const v2f Ec  = {fexp2(cs.x), fexp2(cs.y)};
    const v2f den = (one + Eo) * (one + Ec);
    const float Rd = frcp(den.x * den.y);          // pair-shared reciprocal
    const v2f Roc = {Rd * den.y, Rd * den.x};
    return (Ec - one) * Roc;                       // o * tanh(c)
}

// ---------- kernel 1: transpose x (B,T,F) f32 -> (T,F,B) packed (lo16<<16 | hi16) ----------
__global__ __launch_bounds__(256) void transpose_pack(const float* __restrict__ x,
                                                      unsigned* __restrict__ xt) {
    __shared__ float tile[32][33];
    const int t  = blockIdx.z;
    const int bb = blockIdx.x * 32;
    const int ff = blockIdx.y * 32;
    const int tx = threadIdx.x;   // 0..31
    const int ty = threadIdx.y;   // 0..7
#pragma unroll
    for (int i = 0; i < 4; ++i) {
        int brow = ty + i * 8;
        tile[brow][tx] = x[((size_t)(bb + brow) * Tn + t) * Fn + (ff + tx)];
    }
    __syncthreads();
#pragma unroll
    for (int i = 0; i < 4; ++i) {
        int frow = ty + i * 8;
        float v = tile[tx][frow];
        unsigned hb = bf16bits(v);
        unsigned lb = bf16bits(v - fromhi(hb));
        xt[((size_t)t * Fn + (ff + frow)) * Bsz + (bb + tx)] = hb | (lb << 16);
    }
}

// ---------- kernel 2: recurrent LSTM via MFMA, zero LDS, 4 MFMA/step ----------
// wave = 1 feature x 16 batches; lane (col,gq) owns D rows 4gq..4gq+3 of
// batch col AND (shared believed k-map, validated r7-r11) its own B slots.
// Single MFMA per gate:
//   A = [W_hi (plane0) | gq<2: W_lo quads; gq2: {wxh,wxh}; gq3: {wxl,0}]
//   B = [h (plane0)    | gq<2: h again;    gq>=2: {x_hi,x_lo}, 0]
//   C = fp32 bias (AGPR)
// h is SINGLE bf16 (h_lo dropped); 8 of 16 W_lo*h terms displaced by the
// x-slots — both errors bounded ~e-4 at output (analysis in journal).
__global__ __launch_bounds__(256, 4) void lstm_fwd(const unsigned* __restrict__ xt,  // (T,F,B) packed
                                                   const float* __restrict__ Wih,    // (F,64)
                                                   const float* __restrict__ Whh,    // (F,64,16)
                                                   const float* __restrict__ bih,    // (F,64)
                                                   const float* __restrict__ bhh,    // (F,64)
                                                   const float* __restrict__ init_h,
                                                   const float* __restrict__ init_c,
                                                   float* __restrict__ hout) {       // (B, F*16)
    const int tid  = threadIdx.x;
    const int wv   = tid >> 6;
    const int lane = tid & 63;
    const int gq   = lane >> 4;          // k-quad group / D-row-group
    const int col  = lane & 15;          // A: M-row; B,D: batch col
    const int f    = blockIdx.x >> 4;
    const int bc   = ((blockIdx.x & 15) << 2) | wv;
    const int bglob = bc * 16 + col;

    // ---- persistent fragments (weights pre-scaled into exp2 domain) ----
    s16x8 Aw[4];
    f32x4 biasC[4];
#pragma unroll
    for (int g = 0; g < 4; ++g) {
        const float s = (g == 2) ? L2E2 : -LOG2E;
        const float* wrow = Whh + ((size_t)f * 64 + g * 16 + col) * 16;
        float v0 = wrow[4 * gq + 0] * s, v1 = wrow[4 * gq + 1] * s;
        float v2 = wrow[4 * gq + 2] * s, v3 = wrow[4 * gq + 3] * s;
        unsigned h0 = bf16bits(v0), h1 = bf16bits(v1);
        unsigned h2 = bf16bits(v2), h3 = bf16bits(v3);
        FragU a;
        a.u[0] = h0 | (h1 << 16);        // W_hi quad (plane 0)
        a.u[1] = h2 | (h3 << 16);
        if (gq < 2) {                    // plane 1: W_lo quad
            a.u[2] = bf16bits(v0 - fromhi(h0)) | (bf16bits(v1 - fromhi(h1)) << 16);
            a.u[3] = bf16bits(v2 - fromhi(h2)) | (bf16bits(v3 - fromhi(h3)) << 16);
        } else {                         // plane 1: x-slots
            const float wx = Wih[(size_t)f * 64 + g * 16 + col] * s;
            const unsigned wxh = bf16bits(wx);
            const unsigned wxl = bf16bits(wx - fromhi(wxh));
            a.u[2] = (gq == 2) ? (wxh | (wxh << 16))   // wxh*x_hi + wxh*x_lo
                               : wxl;                  // wxl*x_hi
            a.u[3] = 0u;
        }
        Aw[g] = a.v;
        const size_t bb = (size_t)f * 64 + g * 16 + gq * 4;
        biasC[g] = f32x4{(bih[bb + 0] + bhh[bb + 0]) * s, (bih[bb + 1] + bhh[bb + 1]) * s,
                         (bih[bb + 2] + bhh[bb + 2]) * s, (bih[bb + 3] + bhh[bb + 3]) * s};
    }

    v2f c01, c23, h01, h23;
    {
        const int base = f * 16 + gq * 4;
        c01 = v2f{init_c[base + 0], init_c[base + 1]};
        c23 = v2f{init_c[base + 2], init_c[base + 3]};
        h01 = v2f{init_h[base + 0], init_h[base + 1]};
        h23 = v2f{init_h[base + 2], init_h[base + 3]};
    }

    unsigned p0 = cvtpk(h01.x, h01.y);
    unsigned p1 = cvtpk(h23.x, h23.y);

    const bool hpath = (gq < 2);         // B plane-1 content select
    const unsigned* __restrict__ xp = xt + (size_t)f * Bsz + bglob;
    unsigned xw = xp[0];

    for (int t = 0; t < Tn; ++t) {
        const unsigned xnext = xp[(t + 1 < Tn) ? Fn * Bsz : 0];
        xp += Fn * Bsz;

        FragU b;
        b.u[0] = p0;
        b.u[1] = p1;
        b.u[2] = hpath ? p0 : xw;
        b.u[3] = hpath ? p1 : 0u;

        const f32x4 acc0 = __builtin_amdgcn_mfma_f32_16x16x32_bf16(Aw[0], b.v, biasC[0], 0, 0, 0);
        const f32x4 acc1 = __builtin_amdgcn_mfma_f32_16x16x32_bf16(Aw[1], b.v, biasC[1], 0, 0, 0);
        const f32x4 acc2 = __builtin_amdgcn_mfma_f32_16x16x32_bf16(Aw[2], b.v, biasC[2], 0, 0, 0);
        const f32x4 acc3 = __builtin_amdgcn_mfma_f32_16x16x32_bf16(Aw[3], b.v, biasC[3], 0, 0, 0);

        h01 = act_pair(__builtin_shufflevector(acc0, acc0, 0, 1),
                       __builtin_shufflevector(acc1, acc1, 0, 1),
                       __builtin_shufflevector(acc2, acc2, 0, 1),
                       __builtin_shufflevector(acc3, acc3, 0, 1), c01);
        h23 = act_pair(__builtin_shufflevector(acc0, acc0, 2, 3),
                       __builtin_shufflevector(acc1, acc1, 2, 3),
                       __builtin_shufflevector(acc2, acc2, 2, 3),
                       __builtin_shufflevector(acc3, acc3, 2, 3), c23);

        p0 = cvtpk(h01.x, h01.y);
        p1 = cvtpk(h23.x, h23.y);
        xw = xnext;
    }

    *(f32x4*)(&hout[(size_t)bglob * (Fn * 16) + f * 16 + gq * 4]) =
        f32x4{h01.x, h01.y, h23.x, h23.y};
}

// ---------- kernel 3: out[b] = b_fuse + sum_k hout[b][k]*W_fuse[k] ----------
__global__ __launch_bounds__(256) void fuse_out(const float* __restrict__ hout,
                                                const float* __restrict__ Wf,
                                                const float* __restrict__ bfu,
                                                float* __restrict__ out) {
    __shared__ float part[4];
    const int b = blockIdx.x, tid = threadIdx.x;
    float acc = 0.0f;
#pragma unroll
    for (int q = 0; q < 8; ++q) {
        const int k = q * 256 + tid;
        acc = __fmaf_rn(hout[(size_t)b * (Fn * 16) + k], Wf[k], acc);
    }
#pragma unroll
    for (int off = 32; off; off >>= 1) acc += __shfl_down(acc, off, 64);
    if ((tid & 63) == 0) part[tid >> 6] = acc;
    __syncthreads();
    if (tid == 0) out[b] = part[0] + part[1] + part[2] + part[3] + bfu[0];
}

extern "C" void kernel_launch(void* const* d_in, const int* in_sizes, int n_in,
                              void* d_out, int out_size, void* d_ws, size_t ws_size,
                              hipStream_t stream) {
    const float* x      = (const float*)d_in[0];
    const float* Wih    = (const float*)d_in[1];
    const float* Whh    = (const float*)d_in[2];
    const float* bih    = (const float*)d_in[3];
    const float* bhh    = (const float*)d_in[4];
    const float* init_h = (const float*)d_in[5];
    const float* init_c = (const float*)d_in[6];
    const float* Wf     = (const float*)d_in[7];
    const float* bf     = (const float*)d_in[8];
    float* out = (float*)d_out;

    char* ws = (char*)d_ws;
    unsigned* xtp = (unsigned*)ws;                      // (T,F,B) u32 = 134,217,728 B
    float* hout   = (float*)(ws + (size_t)134217728);   // (B, F*16) = 8,388,608 B

    transpose_pack<<<dim3(32, 4, 256), dim3(32, 8), 0, stream>>>(x, xtp);
    lstm_fwd<<<2048, 256, 0, stream>>>(xtp, Wih, Whh, bih, bhh, init_h, init_c, hout);
    fuse_out<<<Bsz, 256, 0, stream>>>(hout, Wf, bf, out);
}